// Round 2
// baseline (2343.671 us; speedup 1.0000x reference)
//
#include <hip/hip_runtime.h>

// Problem constants (fixed by the reference: N=65536, K=4096, D=128).
constexpr int N_PTS   = 65536;
constexpr int K_CENT  = 4096;
constexpr int D_DIM   = 128;
constexpr int KCHUNKS = 4;                 // split K across grid.y for occupancy
constexpr int KC      = K_CENT / KCHUNKS;  // 1024 centroids per chunk

// ---------------------------------------------------------------------------
// Kernel 1: c2[k] = sum_d coords[k][d]^2
// ---------------------------------------------------------------------------
__global__ __launch_bounds__(256) void c2_kernel(const float* __restrict__ coords,
                                                 float* __restrict__ c2) {
    int k = blockIdx.x * 256 + threadIdx.x;
    if (k >= K_CENT) return;
    const float* c = coords + (size_t)k * D_DIM;
    float s = 0.f;
#pragma unroll
    for (int d = 0; d < D_DIM; ++d) s = fmaf(c[d], c[d], s);
    c2[k] = s;
}

// ---------------------------------------------------------------------------
// Kernel 2: per-point partial argmin over one K-chunk.
// One point per thread. Latent row held in 32 NAMED float4 variables (no
// array -> no alloca -> guaranteed VGPR residency; round-1's float lat[128]
// fell to scratch: VGPR_Count=72, FETCH_SIZE=45 GB).
// coords accessed at full-wave-uniform addresses -> s_load -> SGPR broadcast;
// inner loop is pure v_fmac_f32 (vector dst, sgpr coord, vgpr latent).
// score = c2[k] - 2*dot (x^2 per-point constant; sqrt monotone).
// ---------------------------------------------------------------------------

#define REP32(M) M(0) M(1) M(2) M(3) M(4) M(5) M(6) M(7) \
                 M(8) M(9) M(10) M(11) M(12) M(13) M(14) M(15) \
                 M(16) M(17) M(18) M(19) M(20) M(21) M(22) M(23) \
                 M(24) M(25) M(26) M(27) M(28) M(29) M(30) M(31)

__global__ __launch_bounds__(256, 2) void argmin_partial(
        const float* __restrict__ latent,
        const float* __restrict__ coords,
        const float* __restrict__ c2,
        float* __restrict__ part_score,
        int*   __restrict__ part_idx) {
    const int chunk = blockIdx.y;
    const int n = blockIdx.x * 256 + threadIdx.x;

    // Load this point's latent row into 32 named float4 registers.
    const float* lp = latent + (size_t)n * D_DIM;
#define DECL_LAT(i) float4 lat##i = *(const float4*)(lp + 4 * (i));
    REP32(DECL_LAT)
#undef DECL_LAT

    // Wave-uniform chunk base (readfirstlane makes uniformity explicit).
    const int k0 = __builtin_amdgcn_readfirstlane(chunk * KC);

    float best  = 3.4e38f;
    int   besti = k0;

    for (int k = k0; k < k0 + KC; k += 2) {
        const float* cp = coords + (size_t)k * D_DIM;  // wave-uniform address
        float a0 = 0.f, a1 = 0.f, a2 = 0.f, a3 = 0.f;  // centroid k
        float b0 = 0.f, b1 = 0.f, b2 = 0.f, b3 = 0.f;  // centroid k+1
#define STEP(i) \
        a0 = fmaf(cp[4 * i + 0],         lat##i.x, a0); \
        a1 = fmaf(cp[4 * i + 1],         lat##i.y, a1); \
        a2 = fmaf(cp[4 * i + 2],         lat##i.z, a2); \
        a3 = fmaf(cp[4 * i + 3],         lat##i.w, a3); \
        b0 = fmaf(cp[D_DIM + 4 * i + 0], lat##i.x, b0); \
        b1 = fmaf(cp[D_DIM + 4 * i + 1], lat##i.y, b1); \
        b2 = fmaf(cp[D_DIM + 4 * i + 2], lat##i.z, b2); \
        b3 = fmaf(cp[D_DIM + 4 * i + 3], lat##i.w, b3);
        REP32(STEP)
#undef STEP
        float s0 = fmaf(-2.f, (a0 + a1) + (a2 + a3), c2[k]);
        float s1 = fmaf(-2.f, (b0 + b1) + (b2 + b3), c2[k + 1]);
        // Ascending k with strict < keeps the FIRST minimum (jnp.argmin rule).
        if (s0 < best) { best = s0; besti = k; }
        if (s1 < best) { best = s1; besti = k + 1; }
    }

    part_score[(size_t)chunk * N_PTS + n] = best;
    part_idx  [(size_t)chunk * N_PTS + n] = besti;
}

// ---------------------------------------------------------------------------
// Kernel 3: combine the KCHUNKS candidates per point (chunk-ascending scan,
// strict < preserves lowest-index-on-tie).
// ---------------------------------------------------------------------------
__global__ __launch_bounds__(256) void argmin_combine(
        const float* __restrict__ part_score,
        const int*   __restrict__ part_idx,
        int*         __restrict__ out) {
    const int n = blockIdx.x * 256 + threadIdx.x;
    float best  = part_score[n];
    int   besti = part_idx[n];
#pragma unroll
    for (int c = 1; c < KCHUNKS; ++c) {
        float s = part_score[(size_t)c * N_PTS + n];
        int   i = part_idx  [(size_t)c * N_PTS + n];
        if (s < best) { best = s; besti = i; }
    }
    out[n] = besti;
}

// ---------------------------------------------------------------------------
extern "C" void kernel_launch(void* const* d_in, const int* in_sizes, int n_in,
                              void* d_out, int out_size, void* d_ws, size_t ws_size,
                              hipStream_t stream) {
    const float* latent = (const float*)d_in[0];  // [N, D] fp32
    const float* coords = (const float*)d_in[1];  // [K, D] fp32
    int* out = (int*)d_out;                       // [N] int32 indices

    // Workspace layout: scores[KCHUNKS][N] | idxs[KCHUNKS][N] | c2[K]
    float* part_score = (float*)d_ws;
    int*   part_idx   = (int*)(part_score + (size_t)KCHUNKS * N_PTS);
    float* c2         = (float*)(part_idx + (size_t)KCHUNKS * N_PTS);

    c2_kernel<<<dim3((K_CENT + 255) / 256), dim3(256), 0, stream>>>(coords, c2);

    dim3 grid(N_PTS / 256, KCHUNKS);
    argmin_partial<<<grid, dim3(256), 0, stream>>>(latent, coords, c2,
                                                   part_score, part_idx);

    argmin_combine<<<dim3(N_PTS / 256), dim3(256), 0, stream>>>(part_score,
                                                                part_idx, out);
}